// Round 32
// baseline (92.204 us; speedup 1.0000x reference)
//
#include <hip/hip_runtime.h>
#include <hip/hip_bf16.h>

typedef unsigned short u16;
typedef __bf16 bf16x8 __attribute__((ext_vector_type(8)));
typedef float f32x4 __attribute__((ext_vector_type(4)));
typedef u16 u16x8 __attribute__((ext_vector_type(8)));
typedef u16 u16x4 __attribute__((ext_vector_type(4)));

__device__ __forceinline__ u16 f2bf(float f) {
    unsigned u = __builtin_bit_cast(unsigned, f);
    unsigned r = u + 0x7FFFu + ((u >> 16) & 1u);
    return (u16)(r >> 16);
}
__device__ __forceinline__ float bf2f(u16 h) {
    return __builtin_bit_cast(float, (unsigned)h << 16);
}
__device__ __forceinline__ unsigned cvt_pk_bf16(float lo, float hi) {
    unsigned r;
    asm("v_cvt_pk_bf16_f32 %0, %1, %2" : "=v"(r) : "v"(lo), "v"(hi));
    return r;
}
__device__ __forceinline__ void gload16(const void* g, void* l) {
    __builtin_amdgcn_global_load_lds((const __attribute__((address_space(1))) void*)g,
                                     (__attribute__((address_space(3))) void*)l, 16, 0, 0);
}

// ---------- fused fp32 -> bf16 convert of x | Wqkv | Wo into contiguous ws ----------
__global__ __launch_bounds__(256) void cvt_all(const float* __restrict__ x,
                                               const float* __restrict__ wqkv,
                                               const float* __restrict__ wo,
                                               u16* __restrict__ dst, int n0, int n1) {
    int i = (blockIdx.x * 256 + threadIdx.x) * 4;
    const float* src;
    if (i < n0)            src = x + i;
    else if (i < n0 + n1)  src = wqkv + (i - n0);
    else                   src = wo + (i - n0 - n1);
    float4 v = *(const float4*)src;
    u16x4 o;
    o[0] = f2bf(v.x); o[1] = f2bf(v.y); o[2] = f2bf(v.z); o[3] = f2bf(v.w);
    *(u16x4*)(dst + i) = o;
}

// ------------- deep-pipelined bf16 GEMM: C[M][N] = A[M][K] * Bt[N][K]^T -------------
// BK=64, double-buffered LDS, XOR-swizzled tiles, 8 waves. SINGLE-barrier loop:
// vmcnt(0)[only tile-t loads in flight] -> barrier -> STAGE(t+1) -> compute(t).
// Champion configuration (604-611 TF = the measured structural ceiling of the
// 2-phase stage->vmcnt->barrier family on this shape).
// FUSE_ROPE (qkv, needs 64-col wave span): epilogue RoPE+RMSNorm on q/k heads
// and DIRECT-TRANSPOSED V store into vT[bh][d][s].
template <int BM, int BN, int WR, int WC, bool OUT_BF16, bool FUSE_ROPE>
__global__ __launch_bounds__(WR * WC * 64, (WR * WC == 8) ? 4 : 2)
void gemm_pipe(const u16* __restrict__ A,
               const u16* __restrict__ Bt,
               void* __restrict__ C,
               int M, int N, int K,
               const float* __restrict__ cosc,
               const float* __restrict__ sinc,
               const int* __restrict__ pos_ids,
               u16* __restrict__ vT, int S) {
    constexpr int NW = WR * WC;
    constexpr int MR = BM / WR / 16, NR = BN / WC / 16;
    constexpr int MGS = (MR >= 4) ? 4 : MR;       // MFMA group rows
    constexpr int CA = BM / 8, CB = BN / 8;       // 1KB staging chunks (8 rows x 128B)
    constexpr int CAW = CA / NW, CBW = CB / NW;   // chunks per wave
    static_assert(!FUSE_ROPE || NR == 4, "FUSE_ROPE needs 64-col wave span");

    __shared__ u16 lA[2][BM * 64];
    __shared__ u16 lB[2][BN * 64];

    const int tid = threadIdx.x, lane = tid & 63, w = tid >> 6;
    const int wr = w / WC, wc = w % WC;
    const int lr = lane & 15, lg = lane >> 4;
    const int sw = (lr & 7) << 4;                 // read-side swizzle (bytes)
    const int bm = blockIdx.x * BM, bn = blockIdx.y * BN;
    const int jr = lane >> 3;                     // row within 8-row chunk
    const int scbe = ((((lane & 7) * 16) ^ (jr << 4)) >> 1); // pre-swizzled src col (elems)
    const int nTk = K >> 6;

    f32x4 acc[MR][NR];
#pragma unroll
    for (int i = 0; i < MR; i++)
#pragma unroll
        for (int j = 0; j < NR; j++) acc[i][j] = (f32x4){0.f, 0.f, 0.f, 0.f};

    const u16* aSrc = A + (size_t)bm * K + scbe;
    const u16* bSrc = Bt + (size_t)bn * K + scbe;

#define STAGEP(p_, t_)                                                           \
    {                                                                            \
        _Pragma("unroll") for (int q = 0; q < CAW; q++) {                        \
            int ck = w * CAW + q;                                                \
            gload16(aSrc + (size_t)(ck * 8 + jr) * K + (t_) * 64,                \
                    &lA[p_][ck * 512]);                                          \
        }                                                                        \
        _Pragma("unroll") for (int q = 0; q < CBW; q++) {                        \
            int ck = w * CBW + q;                                                \
            gload16(bSrc + (size_t)(ck * 8 + jr) * K + (t_) * 64,                \
                    &lB[p_][ck * 512]);                                          \
        }                                                                        \
    }

    STAGEP(0, 0);

    for (int t = 0; t < nTk; t++) {
        const int p = t & 1;
        asm volatile("s_waitcnt vmcnt(0)" ::: "memory");   // tile-t loads landed
        __builtin_amdgcn_s_barrier();
        __builtin_amdgcn_sched_barrier(0);        // keep ds_reads below the barrier
        if (t + 1 < nTk) STAGEP(p ^ 1, t + 1);

        const char* pa = (const char*)&lA[p][0] + (size_t)(wr * MR * 16) * 128;
        const char* pb = (const char*)&lB[p][0] + (size_t)(wc * NR * 16) * 128;
#pragma unroll
        for (int ks = 0; ks < 2; ks++) {
            bf16x8 bfr[NR];
#pragma unroll
            for (int j = 0; j < NR; j++)
                bfr[j] = *(const bf16x8*)(pb + (j * 16 + lr) * 128 +
                                          ((ks * 64 + lg * 16) ^ sw));
#pragma unroll
            for (int mg = 0; mg < MR; mg += MGS) {
                bf16x8 af[MGS];
#pragma unroll
                for (int i = 0; i < MGS; i++)
                    af[i] = *(const bf16x8*)(pa + ((mg + i) * 16 + lr) * 128 +
                                             ((ks * 64 + lg * 16) ^ sw));
                __builtin_amdgcn_s_setprio(1);
#pragma unroll
                for (int i = 0; i < MGS; i++)
#pragma unroll
                    for (int j = 0; j < NR; j++)
                        acc[mg + i][j] = __builtin_amdgcn_mfma_f32_16x16x32_bf16(
                            af[i], bfr[j], acc[mg + i][j], 0, 0, 0);
                __builtin_amdgcn_s_setprio(0);
            }
        }
    }
#undef STAGEP

    const int row0 = bm + wr * MR * 16, col0 = bn + wc * NR * 16;

    if constexpr (FUSE_ROPE) {
        u16* Cb = (u16*)C;
        if (col0 < 2048) {
            // q or k head: RoPE + RMSNorm; q additionally scaled 0.125*log2(e)
            const float qs = (col0 < 1024) ? 0.18033688f : 1.0f;
#pragma unroll
            for (int i = 0; i < MR; i++) {
#pragma unroll
                for (int r = 0; r < 4; r++) {
                    const int m = row0 + i * 16 + lg * 4 + r;
                    const int pos = pos_ids[m];
                    const float c0 = cosc[pos * 32 + lr],      s0 = sinc[pos * 32 + lr];
                    const float c1 = cosc[pos * 32 + 16 + lr], s1 = sinc[pos * 32 + 16 + lr];
                    const float x0 = acc[i][0][r], x1 = acc[i][1][r];
                    const float x2 = acc[i][2][r], x3 = acc[i][3][r];
                    const float y0 = x0 * c0 + x2 * s0;
                    const float y2 = x2 * c0 - x0 * s0;
                    const float y1 = x1 * c1 + x3 * s1;
                    const float y3 = x3 * c1 - x1 * s1;
                    float ss = y0 * y0 + y1 * y1 + y2 * y2 + y3 * y3;
                    ss += __shfl_xor(ss, 1);
                    ss += __shfl_xor(ss, 2);
                    ss += __shfl_xor(ss, 4);
                    ss += __shfl_xor(ss, 8);
                    const float scl = rsqrtf(ss * (1.0f / 64.0f) + 1.1920929e-07f) * qs;
                    u16* cp = Cb + (size_t)m * N + col0 + lr;
                    cp[0]  = f2bf(y0 * scl);
                    cp[16] = f2bf(y1 * scl);
                    cp[32] = f2bf(y2 * scl);
                    cp[48] = f2bf(y3 * scl);
                }
            }
        } else {
            // v head: write directly transposed into vT[bh][d][s]
            const int vcol = col0 - 2048;          // 64-aligned head offset
            const int h = vcol >> 6;
            const int b = bm / S;                  // BM divides S -> block-constant
            const int s0 = row0 - b * S + lg * 4;  // token offset within sequence
            u16* vbase = vT + ((size_t)(b * 16 + h) * 64) * S;
#pragma unroll
            for (int i = 0; i < MR; i++) {
                const int s = s0 + i * 16;
#pragma unroll
                for (int j = 0; j < NR; j++) {
                    const int d = j * 16 + lr;
                    u16x4 o;
#pragma unroll
                    for (int r = 0; r < 4; r++) o[r] = f2bf(acc[i][j][r]);
                    *(u16x4*)(vbase + (size_t)d * S + s) = o;
                }
            }
        }
        return;
    }

#pragma unroll
    for (int i = 0; i < MR; i++)
#pragma unroll
        for (int j = 0; j < NR; j++)
#pragma unroll
            for (int r = 0; r < 4; r++) {
                int m = row0 + i * 16 + lg * 4 + r;
                int n = col0 + j * 16 + lr;
                float v = acc[i][j][r];
                if (OUT_BF16)
                    ((u16*)C)[(size_t)m * N + n] = f2bf(v);
                else
                    ((float*)C)[(size_t)m * N + n] = v;
            }
}

// ------- causal flash attention: balanced-pair, DOUBLE-buffered K/V, base-2 -------
// STATIC-MAX softmax (q,k RMS-normed -> |score(log2)| <= 11.54). Q pre-processed
// by the qkv GEMM -> raw fragment load. 40KB LDS -> 4 blocks/CU.
// Schedule: vmcnt(0) -> barrier -> STAGE(s+1) -> compute(s). One barrier/step.
__global__ __launch_bounds__(256, 4) void attn_fwd(const u16* __restrict__ qkv,
                                                   const u16* __restrict__ vT,
                                                   u16* __restrict__ out, int S) {
    const int bh = blockIdx.x, b = bh >> 4, h = bh & 15;
    const int tid = threadIdx.x, lane = tid & 63, w = tid >> 6;
    const int lr = lane & 15, lg = lane >> 4;
    const int sw = (lr & 7) << 4;            // read-side XOR swizzle (byte)

    const int nq = S >> 6;
    const int i1 = blockIdx.y;               // light tile
    const int i2 = (nq - 1) - i1;            // heavy tile
    const int n1 = i1 + 1, ntot = n1 + i2 + 1;

    __shared__ u16 lK[2][64 * 64];           // [kv][d], rows 128B, swizzled
    __shared__ u16 lVt[2][64 * 64];          // [d][kv], rows 128B, swizzled
    __shared__ u16 lP[4][16 * 64];           // per wave: P[q][k], swizzled

    const int jr = lane >> 3;                // row within chunk
    const int cbyte = (lane & 7) * 16;
    const int scb = cbyte ^ (jr << 4);       // pre-swizzled source byte col
    const int rowA = w * 16 + jr, rowB = rowA + 8;
    const u16* kSrc = qkv + 1024 + h * 64 + (scb >> 1);
    const u16* vSrc = vT + (size_t)bh * 64 * S + (scb >> 1);

#define KVOF(x_) ((((x_) < n1) ? (x_) : (x_) - n1) * 64)

#define STAGE(bufi, kv0_)                                                        \
    {                                                                            \
        const u16* kb = kSrc + (size_t)(b * S + (kv0_)) * 3072;                  \
        const u16* vb = vSrc + (kv0_);                                           \
        gload16(kb + (size_t)rowA * 3072, &lK[bufi][(w * 2) * 512]);             \
        gload16(kb + (size_t)rowB * 3072, &lK[bufi][(w * 2 + 1) * 512]);         \
        gload16(vb + (size_t)rowA * S, &lVt[bufi][(w * 2) * 512]);               \
        gload16(vb + (size_t)rowB * S, &lVt[bufi][(w * 2 + 1) * 512]);           \
    }

    bf16x8 bQ[2];
    f32x4 oT[4];
    float lrun;                               // per-lane partial sum of exp2

    // Q stored pre-roped/RMS-normed/scaled -> raw fragment load
#define LOADQ(tile_)                                                             \
    {                                                                            \
        const u16* qp = qkv + (size_t)(b * S + (tile_)*64 + w * 16 + lr) * 3072 + h * 64; \
        bQ[0] = *(const bf16x8*)(qp + lg * 8);                                   \
        bQ[1] = *(const bf16x8*)(qp + 32 + lg * 8);                              \
    }

    STAGE(0, 0);
    LOADQ(i1);
#pragma unroll
    for (int df = 0; df < 4; df++) oT[df] = (f32x4){0.f, 0.f, 0.f, 0.f};
    lrun = 0.f;

    int buf = 0;
    for (int s = 0; s < ntot; s++) {
        const int tile = (s < n1) ? i1 : i2;
        const int kv0 = KVOF(s);
        asm volatile("s_waitcnt vmcnt(0)" ::: "memory");   // tile-s loads landed
        __builtin_amdgcn_s_barrier();
        __builtin_amdgcn_sched_barrier(0);
        if (s + 1 < ntot) STAGE(buf ^ 1, KVOF(s + 1));
        const bool diag = (s == n1 - 1) || (s == ntot - 1);

        // ---- QK^T (swapped): S^T[kv][q] ----
        f32x4 st[4];
#pragma unroll
        for (int kf = 0; kf < 4; kf++) {
            const char* kb = (const char*)&lK[buf][0] + (kf * 16 + lr) * 128;
            bf16x8 k0 = *(const bf16x8*)(kb + ((lg * 16) ^ sw));
            bf16x8 k1 = *(const bf16x8*)(kb + ((64 + lg * 16) ^ sw));
            f32x4 z = (f32x4){0.f, 0.f, 0.f, 0.f};
            z = __builtin_amdgcn_mfma_f32_16x16x32_bf16(k0, bQ[0], z, 0, 0, 0);
            st[kf] = __builtin_amdgcn_mfma_f32_16x16x32_bf16(k1, bQ[1], z, 0, 0, 0);
        }

        // ---- mask (diagonal steps only) + static-max softmax: P = exp2(score) ----
        if (diag) {
            const int qg = tile * 64 + w * 16 + lr;
#pragma unroll
            for (int kf = 0; kf < 4; kf++)
#pragma unroll
                for (int r = 0; r < 4; r++) {
                    int kvg = kv0 + kf * 16 + lg * 4 + r;
                    if (kvg > qg) st[kf][r] = -3.0e38f;
                }
        }
        float ps = 0.f;
#pragma unroll
        for (int kf = 0; kf < 4; kf++)
#pragma unroll
            for (int r = 0; r < 4; r++) {
                float p = exp2f(st[kf][r]);
                st[kf][r] = p;
                ps += p;
            }
        lrun += ps;                           // per-lane partial; reduced at tile end

        // ---- P -> LDS (bf16, swizzled rows of 128B; per-wave region) ----
        {
            char* pb = (char*)&lP[w][0] + lr * 128;
#pragma unroll
            for (int kf = 0; kf < 4; kf++) {
                uint2 pk;
                pk.x = cvt_pk_bf16(st[kf][0], st[kf][1]);
                pk.y = cvt_pk_bf16(st[kf][2], st[kf][3]);
                *(uint2*)(pb + ((kf * 32 + lg * 8) ^ sw)) = pk;
            }
        }

        // ---- PV (swapped): O^T += Vt . P^T ----
#pragma unroll
        for (int kc = 0; kc < 2; kc++) {
            bf16x8 bp = *(const bf16x8*)((const char*)&lP[w][0] + lr * 128 +
                                         ((kc * 64 + lg * 16) ^ sw));
#pragma unroll
            for (int df = 0; df < 4; df++) {
                bf16x8 av = *(const bf16x8*)((const char*)&lVt[buf][0] +
                                             (df * 16 + lr) * 128 +
                                             ((kc * 64 + lg * 16) ^ sw));
                oT[df] = __builtin_amdgcn_mfma_f32_16x16x32_bf16(av, bp, oT[df], 0, 0, 0);
            }
        }

        if (diag) {
            float tot = lrun;
            tot += __shfl_xor(tot, 16);
            tot += __shfl_xor(tot, 32);
            float inv = 1.0f / tot;
            u16* op = out + (size_t)(b * S + tile * 64 + w * 16 + lr) * 1024 +
                      h * 64 + lg * 4;
#pragma unroll
            for (int df = 0; df < 4; df++) {
                u16x4 o;
#pragma unroll
                for (int r = 0; r < 4; r++) o[r] = f2bf(oT[df][r] * inv);
                *(u16x4*)(op + df * 16) = o;
            }
            if (s != ntot - 1) {              // switch to heavy tile
                LOADQ(i2);
#pragma unroll
                for (int df = 0; df < 4; df++) oT[df] = (f32x4){0.f, 0.f, 0.f, 0.f};
                lrun = 0.f;
            }
        }
        buf ^= 1;
    }
#undef STAGE
#undef LOADQ
#undef KVOF
}

extern "C" void kernel_launch(void* const* d_in, const int* in_sizes, int n_in,
                              void* d_out, int out_size, void* d_ws, size_t ws_size,
                              hipStream_t stream) {
    const float* x     = (const float*)d_in[0];
    const float* Wqkv  = (const float*)d_in[1];
    const float* Wo    = (const float*)d_in[2];
    const float* cosc  = (const float*)d_in[3];
    const float* sinc  = (const float*)d_in[4];
    const int* pos_ids = (const int*)d_in[6];

    const int E = 1024, H = 16;
    int S = in_sizes[3] / 32;       // cos_cache is S x 32
    int N = in_sizes[0] / E;
    int B = N / S;

    char* ws = (char*)d_ws;
    u16* xb    = (u16*)ws;                                          // N*E bf16 (reused as attn out)
    u16* wqkvb = (u16*)(ws + (size_t)N * E * 2);                    // 3E*E
    u16* wob   = (u16*)(ws + (size_t)N * E * 2 + (size_t)3 * E * E * 2);
    u16* qkvb  = (u16*)(ws + (size_t)N * E * 2 + (size_t)4 * E * E * 2);
    u16* vTb   = (u16*)(ws + (size_t)N * E * 2 + (size_t)4 * E * E * 2 + (size_t)N * 3 * E * 2);
    u16* aout  = xb;

    // one fused convert: dest segments xb|wqkvb|wob are contiguous in ws
    int n0 = N * E, n1 = 3 * E * E, n2 = E * E;
    cvt_all<<<(n0 + n1 + n2) / 1024, 256, 0, stream>>>(x, Wqkv, Wo, xb, n0, n1);

    // qkv GEMM: 128x128 tiles, 8 waves, single-barrier dbuf; fused RoPE+RMSNorm
    // + transposed V store
    gemm_pipe<128, 128, 4, 2, true, true><<<dim3(N / 128, 3 * E / 128), 512, 0, stream>>>(
        xb, wqkvb, qkvb, N, 3 * E, E, cosc, sinc, pos_ids, vTb, S);

    // attention: balanced-pair blocks, double-buffered staging (4 blocks/CU)
    attn_fwd<<<dim3(B * H, S / 128), 256, 0, stream>>>(qkvb, vTb, aout, S);

    // out GEMM: 64x128 tiles, 8 waves, single-barrier dbuf
    gemm_pipe<64, 128, 2, 4, false, false><<<dim3(N / 64, E / 128), 512, 0, stream>>>(
        aout, wob, d_out, N, E, E, nullptr, nullptr, nullptr, nullptr, 0);
}

// Round 33
// 90.986 us; speedup vs baseline: 1.0134x; 1.0134x over previous
//
#include <hip/hip_runtime.h>
#include <hip/hip_bf16.h>

typedef unsigned short u16;
typedef __bf16 bf16x8 __attribute__((ext_vector_type(8)));
typedef float f32x4 __attribute__((ext_vector_type(4)));
typedef u16 u16x8 __attribute__((ext_vector_type(8)));
typedef u16 u16x4 __attribute__((ext_vector_type(4)));

__device__ __forceinline__ u16 f2bf(float f) {
    unsigned u = __builtin_bit_cast(unsigned, f);
    unsigned r = u + 0x7FFFu + ((u >> 16) & 1u);
    return (u16)(r >> 16);
}
__device__ __forceinline__ float bf2f(u16 h) {
    return __builtin_bit_cast(float, (unsigned)h << 16);
}
__device__ __forceinline__ unsigned cvt_pk_bf16(float lo, float hi) {
    unsigned r;
    asm("v_cvt_pk_bf16_f32 %0, %1, %2" : "=v"(r) : "v"(lo), "v"(hi));
    return r;
}
__device__ __forceinline__ void gload16(const void* g, void* l) {
    __builtin_amdgcn_global_load_lds((const __attribute__((address_space(1))) void*)g,
                                     (__attribute__((address_space(3))) void*)l, 16, 0, 0);
}

// ---------- fused fp32 -> bf16 convert of x | Wqkv | Wo into contiguous ws ----------
__global__ __launch_bounds__(256) void cvt_all(const float* __restrict__ x,
                                               const float* __restrict__ wqkv,
                                               const float* __restrict__ wo,
                                               u16* __restrict__ dst, int n0, int n1) {
    int i = (blockIdx.x * 256 + threadIdx.x) * 4;
    const float* src;
    if (i < n0)            src = x + i;
    else if (i < n0 + n1)  src = wqkv + (i - n0);
    else                   src = wo + (i - n0 - n1);
    float4 v = *(const float4*)src;
    u16x4 o;
    o[0] = f2bf(v.x); o[1] = f2bf(v.y); o[2] = f2bf(v.z); o[3] = f2bf(v.w);
    *(u16x4*)(dst + i) = o;
}

// ------------- deep-pipelined bf16 GEMM: C[M][N] = A[M][K] * Bt[N][K]^T -------------
// BK=64, double-buffered LDS, XOR-swizzled tiles, 8 waves. SINGLE-barrier loop:
// vmcnt(0)[only tile-t loads in flight] -> barrier -> STAGE(t+1) -> compute(t).
// Champion configuration (604-611 TF = the measured structural ceiling of the
// 2-phase stage->vmcnt->barrier family on this shape).
// FUSE_ROPE (qkv, needs 64-col wave span): epilogue RoPE+RMSNorm on q/k heads
// and DIRECT-TRANSPOSED V store into vT[bh][d][s].
template <int BM, int BN, int WR, int WC, bool OUT_BF16, bool FUSE_ROPE>
__global__ __launch_bounds__(WR * WC * 64, (WR * WC == 8) ? 4 : 2)
void gemm_pipe(const u16* __restrict__ A,
               const u16* __restrict__ Bt,
               void* __restrict__ C,
               int M, int N, int K,
               const float* __restrict__ cosc,
               const float* __restrict__ sinc,
               const int* __restrict__ pos_ids,
               u16* __restrict__ vT, int S) {
    constexpr int NW = WR * WC;
    constexpr int MR = BM / WR / 16, NR = BN / WC / 16;
    constexpr int MGS = (MR >= 4) ? 4 : MR;       // MFMA group rows
    constexpr int CA = BM / 8, CB = BN / 8;       // 1KB staging chunks (8 rows x 128B)
    constexpr int CAW = CA / NW, CBW = CB / NW;   // chunks per wave
    static_assert(!FUSE_ROPE || NR == 4, "FUSE_ROPE needs 64-col wave span");

    __shared__ u16 lA[2][BM * 64];
    __shared__ u16 lB[2][BN * 64];

    const int tid = threadIdx.x, lane = tid & 63, w = tid >> 6;
    const int wr = w / WC, wc = w % WC;
    const int lr = lane & 15, lg = lane >> 4;
    const int sw = (lr & 7) << 4;                 // read-side swizzle (bytes)
    const int bm = blockIdx.x * BM, bn = blockIdx.y * BN;
    const int jr = lane >> 3;                     // row within 8-row chunk
    const int scbe = ((((lane & 7) * 16) ^ (jr << 4)) >> 1); // pre-swizzled src col (elems)
    const int nTk = K >> 6;

    f32x4 acc[MR][NR];
#pragma unroll
    for (int i = 0; i < MR; i++)
#pragma unroll
        for (int j = 0; j < NR; j++) acc[i][j] = (f32x4){0.f, 0.f, 0.f, 0.f};

    const u16* aSrc = A + (size_t)bm * K + scbe;
    const u16* bSrc = Bt + (size_t)bn * K + scbe;

#define STAGEP(p_, t_)                                                           \
    {                                                                            \
        _Pragma("unroll") for (int q = 0; q < CAW; q++) {                        \
            int ck = w * CAW + q;                                                \
            gload16(aSrc + (size_t)(ck * 8 + jr) * K + (t_) * 64,                \
                    &lA[p_][ck * 512]);                                          \
        }                                                                        \
        _Pragma("unroll") for (int q = 0; q < CBW; q++) {                        \
            int ck = w * CBW + q;                                                \
            gload16(bSrc + (size_t)(ck * 8 + jr) * K + (t_) * 64,                \
                    &lB[p_][ck * 512]);                                          \
        }                                                                        \
    }

    STAGEP(0, 0);

    for (int t = 0; t < nTk; t++) {
        const int p = t & 1;
        asm volatile("s_waitcnt vmcnt(0)" ::: "memory");   // tile-t loads landed
        __builtin_amdgcn_s_barrier();
        __builtin_amdgcn_sched_barrier(0);        // keep ds_reads below the barrier
        if (t + 1 < nTk) STAGEP(p ^ 1, t + 1);

        const char* pa = (const char*)&lA[p][0] + (size_t)(wr * MR * 16) * 128;
        const char* pb = (const char*)&lB[p][0] + (size_t)(wc * NR * 16) * 128;
#pragma unroll
        for (int ks = 0; ks < 2; ks++) {
            bf16x8 bfr[NR];
#pragma unroll
            for (int j = 0; j < NR; j++)
                bfr[j] = *(const bf16x8*)(pb + (j * 16 + lr) * 128 +
                                          ((ks * 64 + lg * 16) ^ sw));
#pragma unroll
            for (int mg = 0; mg < MR; mg += MGS) {
                bf16x8 af[MGS];
#pragma unroll
                for (int i = 0; i < MGS; i++)
                    af[i] = *(const bf16x8*)(pa + ((mg + i) * 16 + lr) * 128 +
                                             ((ks * 64 + lg * 16) ^ sw));
                __builtin_amdgcn_s_setprio(1);
#pragma unroll
                for (int i = 0; i < MGS; i++)
#pragma unroll
                    for (int j = 0; j < NR; j++)
                        acc[mg + i][j] = __builtin_amdgcn_mfma_f32_16x16x32_bf16(
                            af[i], bfr[j], acc[mg + i][j], 0, 0, 0);
                __builtin_amdgcn_s_setprio(0);
            }
        }
    }
#undef STAGEP

    const int row0 = bm + wr * MR * 16, col0 = bn + wc * NR * 16;

    if constexpr (FUSE_ROPE) {
        u16* Cb = (u16*)C;
        if (col0 < 2048) {
            // q or k head: RoPE + RMSNorm; q additionally scaled 0.125*log2(e)
            const float qs = (col0 < 1024) ? 0.18033688f : 1.0f;
#pragma unroll
            for (int i = 0; i < MR; i++) {
#pragma unroll
                for (int r = 0; r < 4; r++) {
                    const int m = row0 + i * 16 + lg * 4 + r;
                    const int pos = pos_ids[m];
                    const float c0 = cosc[pos * 32 + lr],      s0 = sinc[pos * 32 + lr];
                    const float c1 = cosc[pos * 32 + 16 + lr], s1 = sinc[pos * 32 + 16 + lr];
                    const float x0 = acc[i][0][r], x1 = acc[i][1][r];
                    const float x2 = acc[i][2][r], x3 = acc[i][3][r];
                    const float y0 = x0 * c0 + x2 * s0;
                    const float y2 = x2 * c0 - x0 * s0;
                    const float y1 = x1 * c1 + x3 * s1;
                    const float y3 = x3 * c1 - x1 * s1;
                    float ss = y0 * y0 + y1 * y1 + y2 * y2 + y3 * y3;
                    ss += __shfl_xor(ss, 1);
                    ss += __shfl_xor(ss, 2);
                    ss += __shfl_xor(ss, 4);
                    ss += __shfl_xor(ss, 8);
                    const float scl = rsqrtf(ss * (1.0f / 64.0f) + 1.1920929e-07f) * qs;
                    u16* cp = Cb + (size_t)m * N + col0 + lr;
                    cp[0]  = f2bf(y0 * scl);
                    cp[16] = f2bf(y1 * scl);
                    cp[32] = f2bf(y2 * scl);
                    cp[48] = f2bf(y3 * scl);
                }
            }
        } else {
            // v head: write directly transposed into vT[bh][d][s]
            const int vcol = col0 - 2048;          // 64-aligned head offset
            const int h = vcol >> 6;
            const int b = bm / S;                  // BM divides S -> block-constant
            const int s0 = row0 - b * S + lg * 4;  // token offset within sequence
            u16* vbase = vT + ((size_t)(b * 16 + h) * 64) * S;
#pragma unroll
            for (int i = 0; i < MR; i++) {
                const int s = s0 + i * 16;
#pragma unroll
                for (int j = 0; j < NR; j++) {
                    const int d = j * 16 + lr;
                    u16x4 o;
#pragma unroll
                    for (int r = 0; r < 4; r++) o[r] = f2bf(acc[i][j][r]);
                    *(u16x4*)(vbase + (size_t)d * S + s) = o;
                }
            }
        }
        return;
    }

#pragma unroll
    for (int i = 0; i < MR; i++)
#pragma unroll
        for (int j = 0; j < NR; j++)
#pragma unroll
            for (int r = 0; r < 4; r++) {
                int m = row0 + i * 16 + lg * 4 + r;
                int n = col0 + j * 16 + lr;
                float v = acc[i][j][r];
                if (OUT_BF16)
                    ((u16*)C)[(size_t)m * N + n] = f2bf(v);
                else
                    ((float*)C)[(size_t)m * N + n] = v;
            }
}

// ------- causal flash attention: balanced-pair, DOUBLE-buffered K/V, base-2 -------
// STATIC-MAX softmax (q,k RMS-normed -> |score(log2)| <= 11.54). Q pre-processed
// by the qkv GEMM -> raw fragment load. 40KB LDS -> 4 blocks/CU.
// Schedule: vmcnt(0) -> barrier -> STAGE(s+1) -> compute(s). One barrier/step.
__global__ __launch_bounds__(256, 4) void attn_fwd(const u16* __restrict__ qkv,
                                                   const u16* __restrict__ vT,
                                                   u16* __restrict__ out, int S) {
    const int bh = blockIdx.x, b = bh >> 4, h = bh & 15;
    const int tid = threadIdx.x, lane = tid & 63, w = tid >> 6;
    const int lr = lane & 15, lg = lane >> 4;
    const int sw = (lr & 7) << 4;            // read-side XOR swizzle (byte)

    const int nq = S >> 6;
    const int i1 = blockIdx.y;               // light tile
    const int i2 = (nq - 1) - i1;            // heavy tile
    const int n1 = i1 + 1, ntot = n1 + i2 + 1;

    __shared__ u16 lK[2][64 * 64];           // [kv][d], rows 128B, swizzled
    __shared__ u16 lVt[2][64 * 64];          // [d][kv], rows 128B, swizzled
    __shared__ u16 lP[4][16 * 64];           // per wave: P[q][k], swizzled

    const int jr = lane >> 3;                // row within chunk
    const int cbyte = (lane & 7) * 16;
    const int scb = cbyte ^ (jr << 4);       // pre-swizzled source byte col
    const int rowA = w * 16 + jr, rowB = rowA + 8;
    const u16* kSrc = qkv + 1024 + h * 64 + (scb >> 1);
    const u16* vSrc = vT + (size_t)bh * 64 * S + (scb >> 1);

#define KVOF(x_) ((((x_) < n1) ? (x_) : (x_) - n1) * 64)

#define STAGE(bufi, kv0_)                                                        \
    {                                                                            \
        const u16* kb = kSrc + (size_t)(b * S + (kv0_)) * 3072;                  \
        const u16* vb = vSrc + (kv0_);                                           \
        gload16(kb + (size_t)rowA * 3072, &lK[bufi][(w * 2) * 512]);             \
        gload16(kb + (size_t)rowB * 3072, &lK[bufi][(w * 2 + 1) * 512]);         \
        gload16(vb + (size_t)rowA * S, &lVt[bufi][(w * 2) * 512]);               \
        gload16(vb + (size_t)rowB * S, &lVt[bufi][(w * 2 + 1) * 512]);           \
    }

    bf16x8 bQ[2];
    f32x4 oT[4];
    float lrun;                               // per-lane partial sum of exp2

    // Q stored pre-roped/RMS-normed/scaled -> raw fragment load
#define LOADQ(tile_)                                                             \
    {                                                                            \
        const u16* qp = qkv + (size_t)(b * S + (tile_)*64 + w * 16 + lr) * 3072 + h * 64; \
        bQ[0] = *(const bf16x8*)(qp + lg * 8);                                   \
        bQ[1] = *(const bf16x8*)(qp + 32 + lg * 8);                              \
    }

    STAGE(0, 0);
    LOADQ(i1);
#pragma unroll
    for (int df = 0; df < 4; df++) oT[df] = (f32x4){0.f, 0.f, 0.f, 0.f};
    lrun = 0.f;

    int buf = 0;
    for (int s = 0; s < ntot; s++) {
        const int tile = (s < n1) ? i1 : i2;
        const int kv0 = KVOF(s);
        asm volatile("s_waitcnt vmcnt(0)" ::: "memory");   // tile-s loads landed
        __builtin_amdgcn_s_barrier();
        __builtin_amdgcn_sched_barrier(0);
        if (s + 1 < ntot) STAGE(buf ^ 1, KVOF(s + 1));
        const bool diag = (s == n1 - 1) || (s == ntot - 1);

        // ---- QK^T (swapped): S^T[kv][q] ----
        f32x4 st[4];
#pragma unroll
        for (int kf = 0; kf < 4; kf++) {
            const char* kb = (const char*)&lK[buf][0] + (kf * 16 + lr) * 128;
            bf16x8 k0 = *(const bf16x8*)(kb + ((lg * 16) ^ sw));
            bf16x8 k1 = *(const bf16x8*)(kb + ((64 + lg * 16) ^ sw));
            f32x4 z = (f32x4){0.f, 0.f, 0.f, 0.f};
            z = __builtin_amdgcn_mfma_f32_16x16x32_bf16(k0, bQ[0], z, 0, 0, 0);
            st[kf] = __builtin_amdgcn_mfma_f32_16x16x32_bf16(k1, bQ[1], z, 0, 0, 0);
        }

        // ---- mask (diagonal steps only) + static-max softmax: P = exp2(score) ----
        if (diag) {
            const int qg = tile * 64 + w * 16 + lr;
#pragma unroll
            for (int kf = 0; kf < 4; kf++)
#pragma unroll
                for (int r = 0; r < 4; r++) {
                    int kvg = kv0 + kf * 16 + lg * 4 + r;
                    if (kvg > qg) st[kf][r] = -3.0e38f;
                }
        }
        float ps = 0.f;
#pragma unroll
        for (int kf = 0; kf < 4; kf++)
#pragma unroll
            for (int r = 0; r < 4; r++) {
                float p = exp2f(st[kf][r]);
                st[kf][r] = p;
                ps += p;
            }
        lrun += ps;                           // per-lane partial; reduced at tile end

        // ---- P -> LDS (bf16, swizzled rows of 128B; per-wave region) ----
        {
            char* pb = (char*)&lP[w][0] + lr * 128;
#pragma unroll
            for (int kf = 0; kf < 4; kf++) {
                uint2 pk;
                pk.x = cvt_pk_bf16(st[kf][0], st[kf][1]);
                pk.y = cvt_pk_bf16(st[kf][2], st[kf][3]);
                *(uint2*)(pb + ((kf * 32 + lg * 8) ^ sw)) = pk;
            }
        }

        // ---- PV (swapped): O^T += Vt . P^T ----
#pragma unroll
        for (int kc = 0; kc < 2; kc++) {
            bf16x8 bp = *(const bf16x8*)((const char*)&lP[w][0] + lr * 128 +
                                         ((kc * 64 + lg * 16) ^ sw));
#pragma unroll
            for (int df = 0; df < 4; df++) {
                bf16x8 av = *(const bf16x8*)((const char*)&lVt[buf][0] +
                                             (df * 16 + lr) * 128 +
                                             ((kc * 64 + lg * 16) ^ sw));
                oT[df] = __builtin_amdgcn_mfma_f32_16x16x32_bf16(av, bp, oT[df], 0, 0, 0);
            }
        }

        if (diag) {
            float tot = lrun;
            tot += __shfl_xor(tot, 16);
            tot += __shfl_xor(tot, 32);
            float inv = 1.0f / tot;
            u16* op = out + (size_t)(b * S + tile * 64 + w * 16 + lr) * 1024 +
                      h * 64 + lg * 4;
#pragma unroll
            for (int df = 0; df < 4; df++) {
                u16x4 o;
#pragma unroll
                for (int r = 0; r < 4; r++) o[r] = f2bf(oT[df][r] * inv);
                *(u16x4*)(op + df * 16) = o;
            }
            if (s != ntot - 1) {              // switch to heavy tile
                LOADQ(i2);
#pragma unroll
                for (int df = 0; df < 4; df++) oT[df] = (f32x4){0.f, 0.f, 0.f, 0.f};
                lrun = 0.f;
            }
        }
        buf ^= 1;
    }
#undef STAGE
#undef LOADQ
#undef KVOF
}

extern "C" void kernel_launch(void* const* d_in, const int* in_sizes, int n_in,
                              void* d_out, int out_size, void* d_ws, size_t ws_size,
                              hipStream_t stream) {
    const float* x     = (const float*)d_in[0];
    const float* Wqkv  = (const float*)d_in[1];
    const float* Wo    = (const float*)d_in[2];
    const float* cosc  = (const float*)d_in[3];
    const float* sinc  = (const float*)d_in[4];
    const int* pos_ids = (const int*)d_in[6];

    const int E = 1024, H = 16;
    int S = in_sizes[3] / 32;       // cos_cache is S x 32
    int N = in_sizes[0] / E;
    int B = N / S;

    char* ws = (char*)d_ws;
    u16* xb    = (u16*)ws;                                          // N*E bf16 (reused as attn out)
    u16* wqkvb = (u16*)(ws + (size_t)N * E * 2);                    // 3E*E
    u16* wob   = (u16*)(ws + (size_t)N * E * 2 + (size_t)3 * E * E * 2);
    u16* qkvb  = (u16*)(ws + (size_t)N * E * 2 + (size_t)4 * E * E * 2);
    u16* vTb   = (u16*)(ws + (size_t)N * E * 2 + (size_t)4 * E * E * 2 + (size_t)N * 3 * E * 2);
    u16* aout  = xb;

    // one fused convert: dest segments xb|wqkvb|wob are contiguous in ws
    int n0 = N * E, n1 = 3 * E * E, n2 = E * E;
    cvt_all<<<(n0 + n1 + n2) / 1024, 256, 0, stream>>>(x, Wqkv, Wo, xb, n0, n1);

    // qkv GEMM: 128x128 tiles, 8 waves, single-barrier dbuf; fused RoPE+RMSNorm
    // + transposed V store
    gemm_pipe<128, 128, 4, 2, true, true><<<dim3(N / 128, 3 * E / 128), 512, 0, stream>>>(
        xb, wqkvb, qkvb, N, 3 * E, E, cosc, sinc, pos_ids, vTb, S);

    // attention: balanced-pair blocks, double-buffered staging (4 blocks/CU)
    attn_fwd<<<dim3(B * H, S / 128), 256, 0, stream>>>(qkvb, vTb, aout, S);

    // out GEMM: 64x128 tiles, 8 waves, single-barrier dbuf
    gemm_pipe<64, 128, 2, 4, false, false><<<dim3(N / 64, E / 128), 512, 0, stream>>>(
        aout, wob, d_out, N, E, E, nullptr, nullptr, nullptr, nullptr, 0);
}